// Round 6
// baseline (118.698 us; speedup 1.0000x reference)
//
#include <hip/hip_runtime.h>
#include <hip/hip_bf16.h>
#include <float.h>

// Problem constants (B, N, M from the reference)
#define B_      8
#define N_      8192
#define M_      8192
#define THREADS 256
#define P       8                    // a-points per thread (ILP; 8 indep chains)
#define SPLIT   32                   // M-loop split factor
#define CHUNK   (M_ / SPLIT)         // 256 b-points per block
#define APB     (THREADS * P)        // 2048 a-points per block
#define ATILES  (N_ / APB)           // 4 a-tiles per (batch, dir)
#define NBLOCKS (2 * SPLIT * ATILES * B_)  // 2048 = 8 blocks/CU resident

// Pack xyz [n,3] -> float4 (x, y, z, x^2+y^2+z^2). Serves BOTH sides:
// a-side reads it per-lane (coalesced dwordx4), b-side wave-uniform (s_load).
__global__ void pack_kernel(const float* __restrict__ xyz,
                            float4* __restrict__ out, int n) {
    int i = blockIdx.x * blockDim.x + threadIdx.x;
    if (i < n) {
        float x = xyz[3 * i + 0];
        float y = xyz[3 * i + 1];
        float z = xyz[3 * i + 2];
        out[i] = make_float4(x, y, z, fmaf(x, x, fmaf(y, y, z * z)));
    }
}

// Init output to FLT_MAX (atomicMin target); re-run every call (graph-safe)
__global__ void init_kernel(float* __restrict__ out, int n) {
    int i = blockIdx.x * blockDim.x + threadIdx.x;
    if (i < n) out[i] = FLT_MAX;
}

// Scalar-FMA main kernel. b stays in SGPRs (s_load); each v_fma_f32 reads
// exactly one SGPR operand (legal). Only b.w needs a VGPR copy (1 v_mov per
// b-point, amortized over P=8 a-points). Hot cost: 58 full-rate VALU per
// (2 b x 8 a) = 3.625 ops/pair -> ~50 us execution floor.
__global__ __launch_bounds__(THREADS) void chamfer_s(
    const float4* __restrict__ pk1,   // packed xyz1 [B*N]
    const float4* __restrict__ pk2,   // packed xyz2 [B*M]
    float* __restrict__ out)          // [B*N] dist1 then [B*M] dist2
{
    int bid = blockIdx.x;
    int dir   = bid & 1;                 bid >>= 1;
    int chunk = bid & (SPLIT - 1);       bid /= SPLIT;
    int atile = bid & (ATILES - 1);      bid /= ATILES;
    int batch = bid;                                      // 0..B_-1

    const float4* Ap = dir ? pk2 : pk1;
    const float4* Bp = (dir ? pk1 : pk2) + batch * M_ + chunk * CHUNK;
    float* o = out + (dir ? (B_ * N_) : 0);

    const int a0 = batch * N_ + atile * APB + threadIdx.x;

    float ax2[P], ay2[P], az2[P], m[P];
#pragma unroll
    for (int p = 0; p < P; ++p) {
        float4 a = Ap[a0 + p * THREADS];   // coalesced dwordx4
        ax2[p] = -2.0f * a.x;
        ay2[p] = -2.0f * a.y;
        az2[p] = -2.0f * a.z;
        m[p]   = FLT_MAX;
    }

#pragma unroll 2
    for (int j = 0; j < CHUNK; j += 2) {
        float4 b0 = Bp[j];        // wave-uniform -> s_load_dwordx4 (SGPRs)
        float4 b1 = Bp[j + 1];
        float bw0v, bw1v;
        asm("v_mov_b32 %0, %1" : "=v"(bw0v) : "s"(b0.w));
        asm("v_mov_b32 %0, %1" : "=v"(bw1v) : "s"(b1.w));
#pragma unroll
        for (int p = 0; p < P; ++p) {
            float t0, t1;
            // t = bw - 2*(a . b): 3 FMAs, one SGPR operand each
            asm("v_fma_f32 %0, %1, %2, %3"
                : "=v"(t0) : "v"(az2[p]), "s"(b0.z), "v"(bw0v));
            asm("v_fma_f32 %0, %1, %2, %0"
                : "+v"(t0) : "v"(ay2[p]), "s"(b0.y));
            asm("v_fma_f32 %0, %1, %2, %0"
                : "+v"(t0) : "v"(ax2[p]), "s"(b0.x));
            asm("v_fma_f32 %0, %1, %2, %3"
                : "=v"(t1) : "v"(az2[p]), "s"(b1.z), "v"(bw1v));
            asm("v_fma_f32 %0, %1, %2, %0"
                : "+v"(t1) : "v"(ay2[p]), "s"(b1.y));
            asm("v_fma_f32 %0, %1, %2, %0"
                : "+v"(t1) : "v"(ax2[p]), "s"(b1.x));
            // m = min(m, t0, t1); inputs finite -> NaN semantics moot
            asm("v_min3_f32 %0, %0, %1, %2"
                : "+v"(m[p]) : "v"(t0), "v"(t1));
        }
    }

#pragma unroll
    for (int p = 0; p < P; ++p) {
        float4 a = Ap[a0 + p * THREADS];           // reload for a.w (saves 8 VGPRs)
        float d = fmaxf(a.w + m[p], 0.0f);         // clamp keeps uint-min valid
        atomicMin((unsigned int*)(o + a0 + p * THREADS), __float_as_uint(d));
    }
}

// Fallback if ws too small: raw reads, scalar math (known-good from R2).
#define FP      8
#define FSPLIT  8
#define FCHUNK  (M_ / FSPLIT)
#define FAPB    (THREADS * FP)
#define FATILES (N_ / FAPB)
#define FNBLOCKS (2 * FSPLIT * FATILES * B_)
__global__ __launch_bounds__(THREADS) void chamfer_raw(
    const float* __restrict__ xyz1,
    const float* __restrict__ xyz2,
    float* __restrict__ out)
{
    int bid = blockIdx.x;
    int dir   = bid & 1;                 bid >>= 1;
    int chunk = bid & (FSPLIT - 1);      bid /= FSPLIT;
    int atile = bid & (FATILES - 1);     bid /= FATILES;
    int batch = bid;

    const float* A  = dir ? xyz2 : xyz1;
    const float* Bp = dir ? xyz1 : xyz2;
    float* o = out + (dir ? (B_ * N_) : 0);

    const int a0 = batch * N_ + atile * FAPB + threadIdx.x;

    float ax2[FP], ay2[FP], az2[FP], aw[FP], m[FP];
#pragma unroll
    for (int p = 0; p < FP; ++p) {
        int idx = a0 + p * THREADS;
        float x = A[3 * idx + 0];
        float y = A[3 * idx + 1];
        float z = A[3 * idx + 2];
        ax2[p] = -2.0f * x;
        ay2[p] = -2.0f * y;
        az2[p] = -2.0f * z;
        aw[p]  = fmaf(x, x, fmaf(y, y, z * z));
        m[p]   = FLT_MAX;
    }

    const float* bp = Bp + 3 * (batch * M_ + chunk * FCHUNK);
#pragma unroll 2
    for (int j = 0; j < FCHUNK; j += 2) {
        float b0x = bp[3 * j + 0], b0y = bp[3 * j + 1], b0z = bp[3 * j + 2];
        float b1x = bp[3 * j + 3], b1y = bp[3 * j + 4], b1z = bp[3 * j + 5];
        float b0w = fmaf(b0x, b0x, fmaf(b0y, b0y, b0z * b0z));
        float b1w = fmaf(b1x, b1x, fmaf(b1y, b1y, b1z * b1z));
#pragma unroll
        for (int p = 0; p < FP; ++p) {
            float t0 = fmaf(ax2[p], b0x, b0w);
            t0 = fmaf(ay2[p], b0y, t0);
            t0 = fmaf(az2[p], b0z, t0);
            float t1 = fmaf(ax2[p], b1x, b1w);
            t1 = fmaf(ay2[p], b1y, t1);
            t1 = fmaf(az2[p], b1z, t1);
            m[p] = fminf(m[p], fminf(t0, t1));
        }
    }

#pragma unroll
    for (int p = 0; p < FP; ++p) {
        float d = fmaxf(aw[p] + m[p], 0.0f);
        atomicMin((unsigned int*)(o + a0 + p * THREADS), __float_as_uint(d));
    }
}

extern "C" void kernel_launch(void* const* d_in, const int* in_sizes, int n_in,
                              void* d_out, int out_size, void* d_ws, size_t ws_size,
                              hipStream_t stream) {
    const float* xyz1 = (const float*)d_in[0];
    const float* xyz2 = (const float*)d_in[1];
    float* out = (float*)d_out;

    const int n_out = B_ * N_ + B_ * M_;   // 131072
    init_kernel<<<(n_out + 255) / 256, 256, 0, stream>>>(out, n_out);

    const size_t need = (size_t)(B_ * (N_ + M_)) * sizeof(float4);  // 2 MiB
    if (ws_size >= need) {
        float4* pk1 = (float4*)d_ws;          // [B*N]
        float4* pk2 = pk1 + (size_t)B_ * N_;  // [B*M]
        pack_kernel<<<(B_ * N_ + 255) / 256, 256, 0, stream>>>(xyz1, pk1, B_ * N_);
        pack_kernel<<<(B_ * M_ + 255) / 256, 256, 0, stream>>>(xyz2, pk2, B_ * M_);
        chamfer_s<<<NBLOCKS, THREADS, 0, stream>>>(pk1, pk2, out);
    } else {
        chamfer_raw<<<FNBLOCKS, THREADS, 0, stream>>>(xyz1, xyz2, out);
    }
}

// Round 7
// 118.056 us; speedup vs baseline: 1.0054x; 1.0054x over previous
//
#include <hip/hip_runtime.h>
#include <hip/hip_bf16.h>
#include <float.h>

// Problem constants (B, N, M from the reference)
#define B_      8
#define N_      8192
#define M_      8192
#define THREADS 256
#define P       8                    // a-points per thread (8 indep FMA chains)
#define SPLIT   32                   // M-loop split factor
#define CHUNK   (M_ / SPLIT)         // 256 b-points per block
#define APB     (THREADS * P)        // 2048 a-points per block
#define ATILES  (N_ / APB)           // 4 a-tiles per (batch, dir)
#define NBLOCKS (2 * SPLIT * ATILES * B_)  // 2048

// Pack xyz [n,3] -> float4 (x, y, z, x^2+y^2+z^2). Serves BOTH sides:
// a-side reads it per-lane (coalesced dwordx4), b-side wave-uniform (s_load).
__global__ void pack_kernel(const float* __restrict__ xyz,
                            float4* __restrict__ out, int n) {
    int i = blockIdx.x * blockDim.x + threadIdx.x;
    if (i < n) {
        float x = xyz[3 * i + 0];
        float y = xyz[3 * i + 1];
        float z = xyz[3 * i + 2];
        out[i] = make_float4(x, y, z, fmaf(x, x, fmaf(y, y, z * z)));
    }
}

// Init output to FLT_MAX (atomicMin target); re-run every call (graph-safe)
__global__ void init_kernel(float* __restrict__ out, int n) {
    int i = blockIdx.x * blockDim.x + threadIdx.x;
    if (i < n) out[i] = FLT_MAX;
}

// Scalar-FMA main kernel. b stays in SGPRs (s_load, free pipe); each
// v_fma_f32 reads exactly one SGPR operand (legal). Only b.w needs a VGPR
// copy (1 v_mov per b-point, amortized over P=8 a-points).
// __launch_bounds__(256, 4): REQUIRED — without the ",4" the allocator homes
// the per-thread arrays in AGPRs (VGPR_Count=32) and inserts accvgpr
// read/write around every use: measured ~2x instruction bloat (R2, R6).
__global__ __launch_bounds__(THREADS, 4) void chamfer_s(
    const float4* __restrict__ pk1,   // packed xyz1 [B*N]
    const float4* __restrict__ pk2,   // packed xyz2 [B*M]
    float* __restrict__ out)          // [B*N] dist1 then [B*M] dist2
{
    int bid = blockIdx.x;
    int dir   = bid & 1;                 bid >>= 1;
    int chunk = bid & (SPLIT - 1);       bid /= SPLIT;
    int atile = bid & (ATILES - 1);      bid /= ATILES;
    int batch = bid;                                      // 0..B_-1

    const float4* Ap = dir ? pk2 : pk1;
    const float4* Bp = (dir ? pk1 : pk2) + batch * M_ + chunk * CHUNK;
    float* o = out + (dir ? (B_ * N_) : 0);

    const int a0 = batch * N_ + atile * APB + threadIdx.x;

    float ax2[P], ay2[P], az2[P], aw[P], m[P];
#pragma unroll
    for (int p = 0; p < P; ++p) {
        float4 a = Ap[a0 + p * THREADS];   // coalesced dwordx4
        ax2[p] = -2.0f * a.x;
        ay2[p] = -2.0f * a.y;
        az2[p] = -2.0f * a.z;
        aw[p]  = a.w;
        m[p]   = FLT_MAX;
    }

#pragma unroll 4
    for (int j = 0; j < CHUNK; j += 2) {
        float4 b0 = Bp[j];        // wave-uniform -> s_load (b0,b1 contiguous:
        float4 b1 = Bp[j + 1];    //   compiler can use s_load_dwordx8)
        float bw0v, bw1v;
        asm("v_mov_b32 %0, %1" : "=v"(bw0v) : "s"(b0.w));
        asm("v_mov_b32 %0, %1" : "=v"(bw1v) : "s"(b1.w));
#pragma unroll
        for (int p = 0; p < P; ++p) {
            float t0, t1;
            // t = bw - 2*(a . b): 3 FMAs, one SGPR operand each (legal)
            asm("v_fma_f32 %0, %1, %2, %3"
                : "=v"(t0) : "v"(az2[p]), "s"(b0.z), "v"(bw0v));
            asm("v_fma_f32 %0, %1, %2, %0"
                : "+v"(t0) : "v"(ay2[p]), "s"(b0.y));
            asm("v_fma_f32 %0, %1, %2, %0"
                : "+v"(t0) : "v"(ax2[p]), "s"(b0.x));
            asm("v_fma_f32 %0, %1, %2, %3"
                : "=v"(t1) : "v"(az2[p]), "s"(b1.z), "v"(bw1v));
            asm("v_fma_f32 %0, %1, %2, %0"
                : "+v"(t1) : "v"(ay2[p]), "s"(b1.y));
            asm("v_fma_f32 %0, %1, %2, %0"
                : "+v"(t1) : "v"(ax2[p]), "s"(b1.x));
            // m = min(m, t0, t1); inputs finite -> NaN semantics moot
            asm("v_min3_f32 %0, %0, %1, %2"
                : "+v"(m[p]) : "v"(t0), "v"(t1));
        }
    }

#pragma unroll
    for (int p = 0; p < P; ++p) {
        float d = fmaxf(aw[p] + m[p], 0.0f);     // clamp keeps uint-min valid
        atomicMin((unsigned int*)(o + a0 + p * THREADS), __float_as_uint(d));
    }
}

// Fallback if ws too small: raw reads, scalar math (known-good from R2).
#define FP      8
#define FSPLIT  8
#define FCHUNK  (M_ / FSPLIT)
#define FAPB    (THREADS * FP)
#define FATILES (N_ / FAPB)
#define FNBLOCKS (2 * FSPLIT * FATILES * B_)
__global__ __launch_bounds__(THREADS) void chamfer_raw(
    const float* __restrict__ xyz1,
    const float* __restrict__ xyz2,
    float* __restrict__ out)
{
    int bid = blockIdx.x;
    int dir   = bid & 1;                 bid >>= 1;
    int chunk = bid & (FSPLIT - 1);      bid /= FSPLIT;
    int atile = bid & (FATILES - 1);     bid /= FATILES;
    int batch = bid;

    const float* A  = dir ? xyz2 : xyz1;
    const float* Bp = dir ? xyz1 : xyz2;
    float* o = out + (dir ? (B_ * N_) : 0);

    const int a0 = batch * N_ + atile * FAPB + threadIdx.x;

    float ax2[FP], ay2[FP], az2[FP], aw[FP], m[FP];
#pragma unroll
    for (int p = 0; p < FP; ++p) {
        int idx = a0 + p * THREADS;
        float x = A[3 * idx + 0];
        float y = A[3 * idx + 1];
        float z = A[3 * idx + 2];
        ax2[p] = -2.0f * x;
        ay2[p] = -2.0f * y;
        az2[p] = -2.0f * z;
        aw[p]  = fmaf(x, x, fmaf(y, y, z * z));
        m[p]   = FLT_MAX;
    }

    const float* bp = Bp + 3 * (batch * M_ + chunk * FCHUNK);
#pragma unroll 2
    for (int j = 0; j < FCHUNK; j += 2) {
        float b0x = bp[3 * j + 0], b0y = bp[3 * j + 1], b0z = bp[3 * j + 2];
        float b1x = bp[3 * j + 3], b1y = bp[3 * j + 4], b1z = bp[3 * j + 5];
        float b0w = fmaf(b0x, b0x, fmaf(b0y, b0y, b0z * b0z));
        float b1w = fmaf(b1x, b1x, fmaf(b1y, b1y, b1z * b1z));
#pragma unroll
        for (int p = 0; p < FP; ++p) {
            float t0 = fmaf(ax2[p], b0x, b0w);
            t0 = fmaf(ay2[p], b0y, t0);
            t0 = fmaf(az2[p], b0z, t0);
            float t1 = fmaf(ax2[p], b1x, b1w);
            t1 = fmaf(ay2[p], b1y, t1);
            t1 = fmaf(az2[p], b1z, t1);
            m[p] = fminf(m[p], fminf(t0, t1));
        }
    }

#pragma unroll
    for (int p = 0; p < FP; ++p) {
        float d = fmaxf(aw[p] + m[p], 0.0f);
        atomicMin((unsigned int*)(o + a0 + p * THREADS), __float_as_uint(d));
    }
}

extern "C" void kernel_launch(void* const* d_in, const int* in_sizes, int n_in,
                              void* d_out, int out_size, void* d_ws, size_t ws_size,
                              hipStream_t stream) {
    const float* xyz1 = (const float*)d_in[0];
    const float* xyz2 = (const float*)d_in[1];
    float* out = (float*)d_out;

    const int n_out = B_ * N_ + B_ * M_;   // 131072
    init_kernel<<<(n_out + 255) / 256, 256, 0, stream>>>(out, n_out);

    const size_t need = (size_t)(B_ * (N_ + M_)) * sizeof(float4);  // 2 MiB
    if (ws_size >= need) {
        float4* pk1 = (float4*)d_ws;          // [B*N]
        float4* pk2 = pk1 + (size_t)B_ * N_;  // [B*M]
        pack_kernel<<<(B_ * N_ + 255) / 256, 256, 0, stream>>>(xyz1, pk1, B_ * N_);
        pack_kernel<<<(B_ * M_ + 255) / 256, 256, 0, stream>>>(xyz2, pk2, B_ * M_);
        chamfer_s<<<NBLOCKS, THREADS, 0, stream>>>(pk1, pk2, out);
    } else {
        chamfer_raw<<<FNBLOCKS, THREADS, 0, stream>>>(xyz1, xyz2, out);
    }
}

// Round 8
// 91.362 us; speedup vs baseline: 1.2992x; 1.2922x over previous
//
#include <hip/hip_runtime.h>
#include <hip/hip_bf16.h>
#include <float.h>

// Problem constants (B, N, M from the reference)
#define B_      8
#define N_      8192
#define M_      8192
#define THREADS 256
#define P       4                    // a-points per thread; live set ~30 VGPR
#define SPLIT   16                   // M-loop split factor
#define CHUNK   (M_ / SPLIT)         // 512 b-points per block
#define APB     (THREADS * P)        // 1024 a-points per block
#define ATILES  (N_ / APB)           // 8 a-tiles per (batch, dir)
#define NBLOCKS (2 * SPLIT * ATILES * B_)  // 2048

// Pack xyz [n,3] -> float4 (x, y, z, x^2+y^2+z^2).
__global__ void pack_kernel(const float* __restrict__ xyz,
                            float4* __restrict__ out, int n) {
    int i = blockIdx.x * blockDim.x + threadIdx.x;
    if (i < n) {
        float x = xyz[3 * i + 0];
        float y = xyz[3 * i + 1];
        float z = xyz[3 * i + 2];
        out[i] = make_float4(x, y, z, fmaf(x, x, fmaf(y, y, z * z)));
    }
}

// Init output to FLT_MAX (atomicMin target); re-run every call (graph-safe)
__global__ void init_kernel(float* __restrict__ out, int n) {
    int i = blockIdx.x * blockDim.x + threadIdx.x;
    if (i < n) out[i] = FLT_MAX;
}

// LDS-broadcast main kernel. b-chunk staged once in LDS; hot loop reads it
// with uniform-address ds_read_b128 (broadcast, conflict-free) into VGPRs,
// so every FMA is plain v_fma_f32 v,v,v — no SGPR operands, no v_mov, no
// SMEM stalls. P=4 keeps the working set ~30 VGPRs: small enough that the
// occupancy-greedy allocator (which refused >32 arch VGPRs in R2/R6/R7 and
// shuffled spill through the unified acc file at ~2x instr cost) has no
// reason to evict anything.
__global__ __launch_bounds__(THREADS, 4) void chamfer_lds(
    const float4* __restrict__ pk1,   // packed xyz1 [B*N]
    const float4* __restrict__ pk2,   // packed xyz2 [B*M]
    float* __restrict__ out)          // [B*N] dist1 then [B*M] dist2
{
    __shared__ float4 sb[CHUNK];      // 8 KB

    int bid = blockIdx.x;
    int dir   = bid & 1;                 bid >>= 1;
    int chunk = bid & (SPLIT - 1);       bid /= SPLIT;
    int atile = bid & (ATILES - 1);      bid /= ATILES;
    int batch = bid;                                      // 0..B_-1

    const float4* Ap = dir ? pk2 : pk1;
    const float4* Bp = (dir ? pk1 : pk2) + batch * M_ + chunk * CHUNK;
    float* o = out + (dir ? (B_ * N_) : 0);

    // stage b-chunk into LDS (coalesced dwordx4)
#pragma unroll
    for (int t = threadIdx.x; t < CHUNK; t += THREADS)
        sb[t] = Bp[t];

    const int a0 = batch * N_ + atile * APB + threadIdx.x;

    float ax2[P], ay2[P], az2[P], aw[P], m[P];
#pragma unroll
    for (int p = 0; p < P; ++p) {
        float4 a = Ap[a0 + p * THREADS];   // coalesced dwordx4
        ax2[p] = -2.0f * a.x;
        ay2[p] = -2.0f * a.y;
        az2[p] = -2.0f * a.z;
        aw[p]  = a.w;
        m[p]   = FLT_MAX;
    }

    __syncthreads();

#pragma unroll 4
    for (int j = 0; j < CHUNK; j += 2) {
        float4 b0 = sb[j];        // uniform addr -> ds_read_b128 broadcast
        float4 b1 = sb[j + 1];
#pragma unroll
        for (int p = 0; p < P; ++p) {
            float t0 = fmaf(az2[p], b0.z, b0.w);
            t0 = fmaf(ay2[p], b0.y, t0);
            t0 = fmaf(ax2[p], b0.x, t0);
            float t1 = fmaf(az2[p], b1.z, b1.w);
            t1 = fmaf(ay2[p], b1.y, t1);
            t1 = fmaf(ax2[p], b1.x, t1);
            // m = min(m, t0, t1); inputs finite -> NaN semantics moot.
            // asm also pins m[p] to an arch VGPR.
            asm("v_min3_f32 %0, %0, %1, %2"
                : "+v"(m[p]) : "v"(t0), "v"(t1));
        }
    }

#pragma unroll
    for (int p = 0; p < P; ++p) {
        float d = fmaxf(aw[p] + m[p], 0.0f);     // clamp keeps uint-min valid
        atomicMin((unsigned int*)(o + a0 + p * THREADS), __float_as_uint(d));
    }
}

// Fallback if ws too small: raw reads, scalar math (known-good from R2).
#define FP      8
#define FSPLIT  8
#define FCHUNK  (M_ / FSPLIT)
#define FAPB    (THREADS * FP)
#define FATILES (N_ / FAPB)
#define FNBLOCKS (2 * FSPLIT * FATILES * B_)
__global__ __launch_bounds__(THREADS) void chamfer_raw(
    const float* __restrict__ xyz1,
    const float* __restrict__ xyz2,
    float* __restrict__ out)
{
    int bid = blockIdx.x;
    int dir   = bid & 1;                 bid >>= 1;
    int chunk = bid & (FSPLIT - 1);      bid /= FSPLIT;
    int atile = bid & (FATILES - 1);     bid /= FATILES;
    int batch = bid;

    const float* A  = dir ? xyz2 : xyz1;
    const float* Bp = dir ? xyz1 : xyz2;
    float* o = out + (dir ? (B_ * N_) : 0);

    const int a0 = batch * N_ + atile * FAPB + threadIdx.x;

    float ax2[FP], ay2[FP], az2[FP], aw[FP], m[FP];
#pragma unroll
    for (int p = 0; p < FP; ++p) {
        int idx = a0 + p * THREADS;
        float x = A[3 * idx + 0];
        float y = A[3 * idx + 1];
        float z = A[3 * idx + 2];
        ax2[p] = -2.0f * x;
        ay2[p] = -2.0f * y;
        az2[p] = -2.0f * z;
        aw[p]  = fmaf(x, x, fmaf(y, y, z * z));
        m[p]   = FLT_MAX;
    }

    const float* bp = Bp + 3 * (batch * M_ + chunk * FCHUNK);
#pragma unroll 2
    for (int j = 0; j < FCHUNK; j += 2) {
        float b0x = bp[3 * j + 0], b0y = bp[3 * j + 1], b0z = bp[3 * j + 2];
        float b1x = bp[3 * j + 3], b1y = bp[3 * j + 4], b1z = bp[3 * j + 5];
        float b0w = fmaf(b0x, b0x, fmaf(b0y, b0y, b0z * b0z));
        float b1w = fmaf(b1x, b1x, fmaf(b1y, b1y, b1z * b1z));
#pragma unroll
        for (int p = 0; p < FP; ++p) {
            float t0 = fmaf(ax2[p], b0x, b0w);
            t0 = fmaf(ay2[p], b0y, t0);
            t0 = fmaf(az2[p], b0z, t0);
            float t1 = fmaf(ax2[p], b1x, b1w);
            t1 = fmaf(ay2[p], b1y, t1);
            t1 = fmaf(az2[p], b1z, t1);
            m[p] = fminf(m[p], fminf(t0, t1));
        }
    }

#pragma unroll
    for (int p = 0; p < FP; ++p) {
        float d = fmaxf(aw[p] + m[p], 0.0f);
        atomicMin((unsigned int*)(o + a0 + p * THREADS), __float_as_uint(d));
    }
}

extern "C" void kernel_launch(void* const* d_in, const int* in_sizes, int n_in,
                              void* d_out, int out_size, void* d_ws, size_t ws_size,
                              hipStream_t stream) {
    const float* xyz1 = (const float*)d_in[0];
    const float* xyz2 = (const float*)d_in[1];
    float* out = (float*)d_out;

    const int n_out = B_ * N_ + B_ * M_;   // 131072
    init_kernel<<<(n_out + 255) / 256, 256, 0, stream>>>(out, n_out);

    const size_t need = (size_t)(B_ * (N_ + M_)) * sizeof(float4);  // 2 MiB
    if (ws_size >= need) {
        float4* pk1 = (float4*)d_ws;          // [B*N]
        float4* pk2 = pk1 + (size_t)B_ * N_;  // [B*M]
        pack_kernel<<<(B_ * N_ + 255) / 256, 256, 0, stream>>>(xyz1, pk1, B_ * N_);
        pack_kernel<<<(B_ * M_ + 255) / 256, 256, 0, stream>>>(xyz2, pk2, B_ * M_);
        chamfer_lds<<<NBLOCKS, THREADS, 0, stream>>>(pk1, pk2, out);
    } else {
        chamfer_raw<<<FNBLOCKS, THREADS, 0, stream>>>(xyz1, xyz2, out);
    }
}

// Round 9
// 86.133 us; speedup vs baseline: 1.3781x; 1.0607x over previous
//
#include <hip/hip_runtime.h>
#include <hip/hip_bf16.h>
#include <float.h>

// Problem constants (B, N, M from the reference)
#define B_      8
#define N_      8192
#define M_      8192
#define THREADS 256
#define P       4                    // a-points per thread; live set fits arch VGPRs
#define SPLIT   16                   // M-loop split factor
#define CHUNK   (M_ / SPLIT)         // 512 b-points per block
#define APB     (THREADS * P)        // 1024 a-points per block
#define ATILES  (N_ / APB)           // 8 a-tiles per (batch, dir)
#define NBLOCKS (2 * SPLIT * ATILES * B_)  // 2048

// Fused prologue: pack xyz [n,3] -> float4 (x,y,z,|p|^2) for BOTH inputs AND
// init out[i] = FLT_MAX (atomicMin target). n_total = B*(N+M) == out_size.
__global__ void prep_kernel(const float* __restrict__ xyz1,
                            const float* __restrict__ xyz2,
                            float4* __restrict__ pk,      // [B*N] then [B*M]
                            float* __restrict__ out, int n1, int n_total) {
    int i = blockIdx.x * blockDim.x + threadIdx.x;
    if (i < n_total) {
        const float* src = (i < n1) ? (xyz1 + 3 * i) : (xyz2 + 3 * (i - n1));
        float x = src[0], y = src[1], z = src[2];
        pk[i] = make_float4(x, y, z, fmaf(x, x, fmaf(y, y, z * z)));
        out[i] = FLT_MAX;
    }
}

__global__ void init_kernel(float* __restrict__ out, int n) {
    int i = blockIdx.x * blockDim.x + threadIdx.x;
    if (i < n) out[i] = FLT_MAX;
}

// Hybrid-delivery main kernel: per 4-b supergroup, 2 b-points come from LDS
// broadcast (uniform ds_read_b128) and 2 from wave-uniform global reads of
// the packed array (compiler scalarizes to s_load; SMEM pipe). This halves
// LDS-unit pressure — R8 evidence suggests broadcast ds_read_b128 may cost
// ~12 cyc of the CU-shared LDS pipe, making it the bottleneck at 83 us.
// P=4 keeps live set ~32-40 VGPRs (P=8 triggers the allocator's 32-VGPR +
// AGPR-shuffle mode: ~2x instr bloat, seen R2/R6/R7).
__global__ __launch_bounds__(THREADS, 4) void chamfer_hy(
    const float4* __restrict__ pk1,   // packed xyz1 [B*N]
    const float4* __restrict__ pk2,   // packed xyz2 [B*M]
    float* __restrict__ out)          // [B*N] dist1 then [B*M] dist2
{
    __shared__ float4 sb[CHUNK / 2];  // 4 KB: even-indexed pairs only

    int bid = blockIdx.x;
    int dir   = bid & 1;                 bid >>= 1;
    int chunk = bid & (SPLIT - 1);       bid /= SPLIT;
    int atile = bid & (ATILES - 1);      bid /= ATILES;
    int batch = bid;                                      // 0..B_-1

    const float4* Ap = dir ? pk2 : pk1;
    const float4* Bp = (dir ? pk1 : pk2) + batch * M_ + chunk * CHUNK;
    float* o = out + (dir ? (B_ * N_) : 0);

    // stage the LDS half: b[4k], b[4k+1] for k = 0..CHUNK/4-1
    for (int t = threadIdx.x; t < CHUNK / 2; t += THREADS) {
        int k = t >> 1;           // supergroup
        int r = t & 1;            // 0/1 within pair
        sb[t] = Bp[4 * k + r];
    }

    const int a0 = batch * N_ + atile * APB + threadIdx.x;

    float ax2[P], ay2[P], az2[P], aw[P], m[P];
#pragma unroll
    for (int p = 0; p < P; ++p) {
        float4 a = Ap[a0 + p * THREADS];   // coalesced dwordx4
        ax2[p] = -2.0f * a.x;
        ay2[p] = -2.0f * a.y;
        az2[p] = -2.0f * a.z;
        aw[p]  = a.w;
        m[p]   = FLT_MAX;
    }

    __syncthreads();

#pragma unroll 2
    for (int k = 0; k < CHUNK / 4; ++k) {
        float4 b0 = sb[2 * k + 0];        // LDS broadcast pipe
        float4 b1 = sb[2 * k + 1];
        float4 b2 = Bp[4 * k + 2];        // wave-uniform -> s_load (SMEM pipe)
        float4 b3 = Bp[4 * k + 3];
#pragma unroll
        for (int p = 0; p < P; ++p) {
            float t0 = fmaf(az2[p], b0.z, b0.w);
            t0 = fmaf(ay2[p], b0.y, t0);
            t0 = fmaf(ax2[p], b0.x, t0);
            float t1 = fmaf(az2[p], b1.z, b1.w);
            t1 = fmaf(ay2[p], b1.y, t1);
            t1 = fmaf(ax2[p], b1.x, t1);
            asm("v_min3_f32 %0, %0, %1, %2"
                : "+v"(m[p]) : "v"(t0), "v"(t1));
            float t2 = fmaf(az2[p], b2.z, b2.w);
            t2 = fmaf(ay2[p], b2.y, t2);
            t2 = fmaf(ax2[p], b2.x, t2);
            float t3 = fmaf(az2[p], b3.z, b3.w);
            t3 = fmaf(ay2[p], b3.y, t3);
            t3 = fmaf(ax2[p], b3.x, t3);
            asm("v_min3_f32 %0, %0, %1, %2"
                : "+v"(m[p]) : "v"(t2), "v"(t3));
        }
    }

#pragma unroll
    for (int p = 0; p < P; ++p) {
        float d = fmaxf(aw[p] + m[p], 0.0f);     // clamp keeps uint-min valid
        atomicMin((unsigned int*)(o + a0 + p * THREADS), __float_as_uint(d));
    }
}

// Fallback if ws too small: raw reads, scalar math (known-good from R2).
#define FP      8
#define FSPLIT  8
#define FCHUNK  (M_ / FSPLIT)
#define FAPB    (THREADS * FP)
#define FATILES (N_ / FAPB)
#define FNBLOCKS (2 * FSPLIT * FATILES * B_)
__global__ __launch_bounds__(THREADS) void chamfer_raw(
    const float* __restrict__ xyz1,
    const float* __restrict__ xyz2,
    float* __restrict__ out)
{
    int bid = blockIdx.x;
    int dir   = bid & 1;                 bid >>= 1;
    int chunk = bid & (FSPLIT - 1);      bid /= FSPLIT;
    int atile = bid & (FATILES - 1);     bid /= FATILES;
    int batch = bid;

    const float* A  = dir ? xyz2 : xyz1;
    const float* Bp = dir ? xyz1 : xyz2;
    float* o = out + (dir ? (B_ * N_) : 0);

    const int a0 = batch * N_ + atile * FAPB + threadIdx.x;

    float ax2[FP], ay2[FP], az2[FP], aw[FP], m[FP];
#pragma unroll
    for (int p = 0; p < FP; ++p) {
        int idx = a0 + p * THREADS;
        float x = A[3 * idx + 0];
        float y = A[3 * idx + 1];
        float z = A[3 * idx + 2];
        ax2[p] = -2.0f * x;
        ay2[p] = -2.0f * y;
        az2[p] = -2.0f * z;
        aw[p]  = fmaf(x, x, fmaf(y, y, z * z));
        m[p]   = FLT_MAX;
    }

    const float* bp = Bp + 3 * (batch * M_ + chunk * FCHUNK);
#pragma unroll 2
    for (int j = 0; j < FCHUNK; j += 2) {
        float b0x = bp[3 * j + 0], b0y = bp[3 * j + 1], b0z = bp[3 * j + 2];
        float b1x = bp[3 * j + 3], b1y = bp[3 * j + 4], b1z = bp[3 * j + 5];
        float b0w = fmaf(b0x, b0x, fmaf(b0y, b0y, b0z * b0z));
        float b1w = fmaf(b1x, b1x, fmaf(b1y, b1y, b1z * b1z));
#pragma unroll
        for (int p = 0; p < FP; ++p) {
            float t0 = fmaf(ax2[p], b0x, b0w);
            t0 = fmaf(ay2[p], b0y, t0);
            t0 = fmaf(az2[p], b0z, t0);
            float t1 = fmaf(ax2[p], b1x, b1w);
            t1 = fmaf(ay2[p], b1y, t1);
            t1 = fmaf(az2[p], b1z, t1);
            m[p] = fminf(m[p], fminf(t0, t1));
        }
    }

#pragma unroll
    for (int p = 0; p < FP; ++p) {
        float d = fmaxf(aw[p] + m[p], 0.0f);
        atomicMin((unsigned int*)(o + a0 + p * THREADS), __float_as_uint(d));
    }
}

extern "C" void kernel_launch(void* const* d_in, const int* in_sizes, int n_in,
                              void* d_out, int out_size, void* d_ws, size_t ws_size,
                              hipStream_t stream) {
    const float* xyz1 = (const float*)d_in[0];
    const float* xyz2 = (const float*)d_in[1];
    float* out = (float*)d_out;

    const int n_out = B_ * N_ + B_ * M_;   // 131072

    const size_t need = (size_t)(B_ * (N_ + M_)) * sizeof(float4);  // 2 MiB
    if (ws_size >= need) {
        float4* pk1 = (float4*)d_ws;          // [B*N]; pk2 follows at [B*M]
        prep_kernel<<<(n_out + 255) / 256, 256, 0, stream>>>(
            xyz1, xyz2, pk1, out, B_ * N_, n_out);
        chamfer_hy<<<NBLOCKS, THREADS, 0, stream>>>(pk1, pk1 + (size_t)B_ * N_, out);
    } else {
        init_kernel<<<(n_out + 255) / 256, 256, 0, stream>>>(out, n_out);
        chamfer_raw<<<FNBLOCKS, THREADS, 0, stream>>>(xyz1, xyz2, out);
    }
}